// Round 11
// baseline (159.275 us; speedup 1.0000x reference)
//
#include <hip/hip_runtime.h>
#include <hip/hip_bf16.h>

// R11 = R9 with the attention kernel's LDS deliberately padded to 54KB so
// the backend's occupancy arithmetic gives floor(160/54)=2 WG/CU = 4
// waves/SIMD -> VGPR pressure target 128 (not 64). R7/R9/R10 showed the
// allocator squeezes to 64 VGPR whenever LDS permits 4 WG/CU (8 waves/SIMD),
// sinking the K/V prefetch loads next to their uses and serializing the
// loop (MfmaUtil 10.6%). The grid (512 = 2 blocks/CU) can never reach 8
// waves/SIMD, so that squeeze was pure loss. waves_per_eu/launch_bounds
// hints did NOT move the target (R10: VGPR still 64); LDS size does.

typedef short  s16x8 __attribute__((ext_vector_type(8)));
typedef short  s16x4 __attribute__((ext_vector_type(4)));
typedef float  f32x4 __attribute__((ext_vector_type(4)));
typedef float  f32x16 __attribute__((ext_vector_type(16)));
typedef unsigned int u32;
typedef unsigned int u32x4 __attribute__((ext_vector_type(4)));

__device__ __forceinline__ unsigned short f2bf(float x) {
    return __builtin_bit_cast(unsigned short, __float2bfloat16(x));
}
__device__ __forceinline__ void gload16(const void* g, void* lds) {
    __builtin_amdgcn_global_load_lds(
        (const __attribute__((address_space(1))) unsigned int*)g,
        (__attribute__((address_space(3))) unsigned int*)lds, 16, 0, 0);
}
__device__ __forceinline__ u32 cvtpk(float lo, float hi) {
    u32 r;
    asm("v_cvt_pk_bf16_f32 %0, %1, %2" : "=v"(r) : "v"(lo), "v"(hi));
    return r;
}

// ---------------- prep: cast q,k; transpose/cast W; count masked keys ------
__global__ __launch_bounds__(256) void prep(
    const float* __restrict__ q, const float* __restrict__ k,
    const float* __restrict__ Wq, const float* __restrict__ Wk,
    const float* __restrict__ Wv, const int* __restrict__ mask,
    unsigned short* __restrict__ qbf, unsigned short* __restrict__ kbf,
    unsigned short* __restrict__ wtq, unsigned short* __restrict__ wtk,
    unsigned short* __restrict__ wtv, int* __restrict__ cntb)
{
    __shared__ float T[64][65];
    const int bid = blockIdx.x;
    const int tid = threadIdx.x;
    if (bid < 3072) {
        const float* src = bid < 1024 ? q : k;
        unsigned short* dst = bid < 1024 ? qbf : kbf;
        int i = (bid < 1024 ? bid : bid - 1024) * 256 + tid;
        float4 a = reinterpret_cast<const float4*>(src)[2 * i];
        float4 b = reinterpret_cast<const float4*>(src)[2 * i + 1];
        s16x8 o;
        o[0] = (short)f2bf(a.x); o[1] = (short)f2bf(a.y);
        o[2] = (short)f2bf(a.z); o[3] = (short)f2bf(a.w);
        o[4] = (short)f2bf(b.x); o[5] = (short)f2bf(b.y);
        o[6] = (short)f2bf(b.z); o[7] = (short)f2bf(b.w);
        reinterpret_cast<s16x8*>(dst)[i] = o;
    } else if (bid < 3264) {
        int t = bid - 3072;
        int z = t >> 6;
        int tt = t & 63;
        const float* W = z == 0 ? Wq : z == 1 ? Wk : Wv;
        unsigned short* D = z == 0 ? wtq : z == 1 ? wtk : wtv;
        const int k0 = (tt >> 3) * 64, n0 = (tt & 7) * 64;
        const int r = tid >> 2, cq = tid & 3;
        #pragma unroll
        for (int p = 0; p < 4; ++p) {
            int c = (cq + 4 * p) * 4;
            float4 v = *reinterpret_cast<const float4*>(
                &W[(size_t)(k0 + r) * 512 + n0 + c]);
            T[c + 0][r] = v.x; T[c + 1][r] = v.y;
            T[c + 2][r] = v.z; T[c + 3][r] = v.w;
        }
        __syncthreads();
        #pragma unroll
        for (int p = 0; p < 4; ++p) {
            int kc = (cq + 4 * p) * 4;
            s16x4 o;
            o[0] = (short)f2bf(T[r][kc + 0]);
            o[1] = (short)f2bf(T[r][kc + 1]);
            o[2] = (short)f2bf(T[r][kc + 2]);
            o[3] = (short)f2bf(T[r][kc + 3]);
            *reinterpret_cast<s16x4*>(&D[(size_t)(n0 + r) * 512 + k0 + kc]) = o;
        }
    } else {
        // blocks 3264/3265: per-batch masked-key count (deterministic)
        __shared__ int red[4];
        int b = bid - 3264;
        int base = b * 4096 + tid * 16;
        int s = 0;
        #pragma unroll
        for (int p = 0; p < 4; ++p) {
            int4 m = *reinterpret_cast<const int4*>(&mask[base + 4 * p]);
            s += m.x + m.y + m.z + m.w;
        }
        #pragma unroll
        for (int off = 1; off < 64; off <<= 1)
            s += __shfl_xor(s, off);
        if ((tid & 63) == 0) red[tid >> 6] = s;
        __syncthreads();
        if (tid == 0)
            cntb[b] = 4096 - (red[0] + red[1] + red[2] + red[3]);
    }
}

// ---------------- fused 3-way projection GEMM, bf16 MFMA, 2-phase ----------
// mflag: 0 = none (Q), 1 = zero masked rows (K), 2 = zero masked cols (V^T)
__global__ __launch_bounds__(256) void proj3(
    const unsigned short* __restrict__ qbf, const unsigned short* __restrict__ kbf,
    const unsigned short* __restrict__ wtq, const unsigned short* __restrict__ wtk,
    const unsigned short* __restrict__ wtv,
    const float* __restrict__ bq, const float* __restrict__ bk,
    const float* __restrict__ bv, const int* __restrict__ mask,
    unsigned short* __restrict__ qh, unsigned short* __restrict__ kh,
    unsigned short* __restrict__ vt)
{
    __shared__ unsigned short As[2][128 * 64];
    __shared__ unsigned short Bs[2][64 * 64];

    const int tid  = threadIdx.x;
    const int wv   = tid >> 6;
    const int lane = tid & 63;
    const int g    = lane >> 4;
    const int ln   = lane & 15;
    const int swz  = (ln & 7) << 3;

    const int id = blockIdx.x;
    const unsigned short *A, *Wt;
    const float* bias;
    unsigned short* dst;
    int S, trans, nb, mb, mflag;
    if (id < 256)      { A = qbf; Wt = wtq; bias = bq; dst = qh; S = 2048; trans = 0; mflag = 0; nb = id & 7;         mb = id >> 3; }
    else if (id < 768) { A = kbf; Wt = wtk; bias = bk; dst = kh; S = 4096; trans = 0; mflag = 1; nb = (id - 256) & 7; mb = (id - 256) >> 3; }
    else               { A = kbf; Wt = wtv; bias = bv; dst = vt; S = 4096; trans = 1; mflag = 2; nb = (id - 768) & 7; mb = (id - 768) >> 3; }
    const int m0 = mb * 128, n0 = nb * 64;

    f32x4 acc[4][2];
    #pragma unroll
    for (int i = 0; i < 4; ++i)
        #pragma unroll
        for (int j = 0; j < 2; ++j) acc[i][j] = (f32x4)0.f;

    auto stage = [&](int bufn, int k0) {
        #pragma unroll
        for (int p = 0; p < 4; ++p) {
            int slot = p * 256 + tid;
            int row = slot >> 3, cb = slot & 7;
            int cbp = cb ^ (row & 7);
            gload16(&A[(size_t)(m0 + row) * 512 + k0 + cbp * 8], &As[bufn][slot * 8]);
        }
        #pragma unroll
        for (int p = 0; p < 2; ++p) {
            int slot = p * 256 + tid;
            int row = slot >> 3, cb = slot & 7;
            int cbp = cb ^ (row & 7);
            gload16(&Wt[(size_t)(n0 + row) * 512 + k0 + cbp * 8], &Bs[bufn][slot * 8]);
        }
    };

    stage(0, 0);
    __syncthreads();
    int buf = 0;
    for (int kk = 0; kk < 8; ++kk) {
        if (kk < 7) stage(buf ^ 1, (kk + 1) * 64);
        #pragma unroll
        for (int ks = 0; ks < 2; ++ks) {
            s16x8 fa[2], fb[4];
            #pragma unroll
            for (int mi = 0; mi < 2; ++mi)
                fa[mi] = *reinterpret_cast<const s16x8*>(
                    &As[buf][((wv * 32 + 16 * mi + ln) * 64 + ks * 32 + g * 8) ^ swz]);
            #pragma unroll
            for (int nj = 0; nj < 4; ++nj)
                fb[nj] = *reinterpret_cast<const s16x8*>(
                    &Bs[buf][((16 * nj + ln) * 64 + ks * 32 + g * 8) ^ swz]);
            if (!trans) {
                #pragma unroll
                for (int mi = 0; mi < 2; ++mi)
                    #pragma unroll
                    for (int nj = 0; nj < 4; ++nj)
                        acc[nj][mi] = __builtin_amdgcn_mfma_f32_16x16x32_bf16(
                            fa[mi], fb[nj], acc[nj][mi], 0, 0, 0);
            } else {
                #pragma unroll
                for (int nj = 0; nj < 4; ++nj)
                    #pragma unroll
                    for (int mi = 0; mi < 2; ++mi)
                        acc[nj][mi] = __builtin_amdgcn_mfma_f32_16x16x32_bf16(
                            fb[nj], fa[mi], acc[nj][mi], 0, 0, 0);
            }
        }
        __syncthreads();
        buf ^= 1;
    }

    const int h    = nb;
    const int bidx = m0 / S;
    const int s0   = m0 - bidx * S;

    if (!trans) {
        float bvv[4];
        #pragma unroll
        for (int nj = 0; nj < 4; ++nj) bvv[nj] = bias[n0 + 16 * nj + ln];
        unsigned short* base = dst + (size_t)(bidx * 8 + h) * S * 64;
        #pragma unroll
        for (int mi = 0; mi < 2; ++mi)
            #pragma unroll
            for (int r = 0; r < 4; ++r) {
                int s = s0 + wv * 32 + 16 * mi + 4 * g + r;
                float fm = (mflag == 1) ? (float)mask[bidx * 4096 + s] : 1.f;
                #pragma unroll
                for (int nj = 0; nj < 4; ++nj)
                    base[(size_t)s * 64 + 16 * nj + ln] =
                        f2bf((acc[nj][mi][r] + bvv[nj]) * fm);
            }
    } else {
        float fmc[2];
        #pragma unroll
        for (int mi = 0; mi < 2; ++mi)
            fmc[mi] = (float)mask[bidx * 4096 + s0 + wv * 32 + 16 * mi + ln];
        unsigned short* base = dst + (size_t)(bidx * 8 + h) * 64 * (size_t)S;
        #pragma unroll
        for (int nj = 0; nj < 4; ++nj)
            #pragma unroll
            for (int r = 0; r < 4; ++r) {
                int w = 16 * nj + 4 * g + r;
                float bw = bias[n0 + w];
                #pragma unroll
                for (int mi = 0; mi < 2; ++mi)
                    base[(size_t)w * S + s0 + wv * 32 + 16 * mi + ln] =
                        f2bf((acc[nj][mi][r] + bw) * fmc[mi]);
            }
    }
}

// ---------------- attention: LDS-free loop, 32x32 MFMA, 32q x 32k / wave ---
__global__ __launch_bounds__(512) void attn9(
    const unsigned short* __restrict__ qh,  // [B,8,2048,64] bf16
    const unsigned short* __restrict__ kh,  // [B,8,4096,64] bf16 (masked rows 0)
    const unsigned short* __restrict__ vt,  // [B,8,64,4096] bf16 (masked cols 0)
    const int* __restrict__ cntb,           // [B] masked-key counts
    float* __restrict__ out)                // [B,2048,512]
{
    // NOTE: Ored stride padded 36 -> 53 to push LDS to 54KB on purpose:
    // floor(160KB/54KB) = 2 WG/CU = 4 waves/SIMD -> compiler's VGPR
    // pressure target becomes 128, preventing the 64-VGPR squeeze.
    __shared__ float Ored[2][4][32][53];    // [qg][kq][q32][w32+pad]
    __shared__ float lw[2][4][32];          // [qg][kq][q32]

    const int tid  = threadIdx.x;
    const int wid  = tid >> 6;
    const int kq   = wid & 3;
    const int qg   = wid >> 2;
    const int lane = tid & 63;
    const int l31  = lane & 31;
    const int h32  = lane >> 5;

    const int id  = blockIdx.x;
    const int xcd = id & 7;
    const int j   = id >> 3;
    const int bh  = xcd * 2 + (j >> 5);
    const int qt  = j & 31;
    const int b   = bh >> 3;
    const int hh  = bh & 7;

    const unsigned short* Kp = kh + (size_t)bh * 4096 * 64
                               + (size_t)(kq * 32 + l31) * 64 + h32 * 8;
    const unsigned short* Vp0 = vt + (size_t)bh * 64 * 4096
                               + (size_t)l31 * 4096 + kq * 32 + h32 * 8;

    s16x8 Qf[4];
    {
        const unsigned short* Qb = qh + ((size_t)bh * 2048 + qt * 64 + qg * 32) * 64;
        #pragma unroll
        for (int ks = 0; ks < 4; ++ks)
            Qf[ks] = *reinterpret_cast<const s16x8*>(
                &Qb[(size_t)l31 * 64 + ks * 16 + h32 * 8]);
    }

    f32x16 O[2];
    O[0] = (f32x16)0.f; O[1] = (f32x16)0.f;
    float l_acc = 0.f;

    s16x8 kf[4], vf[4];

    auto loadK = [&](int t) {
        #pragma unroll
        for (int ks = 0; ks < 4; ++ks)
            kf[ks] = *reinterpret_cast<const s16x8*>(Kp + (size_t)t * 8192 + ks * 16);
    };
    auto loadV = [&](int t) {
        #pragma unroll
        for (int wt = 0; wt < 2; ++wt)
            #pragma unroll
            for (int t2 = 0; t2 < 2; ++t2)
                vf[wt * 2 + t2] = *reinterpret_cast<const s16x8*>(
                    Vp0 + (size_t)wt * 32 * 4096 + t * 128 + t2 * 16);
    };

    loadK(0); loadV(0);

    for (int t = 0; t < 32; ++t) {
        // ---- QK^T: S^T[32 keys][32 q] ----------------------------------
        f32x16 S = (f32x16)0.f;
        __builtin_amdgcn_s_setprio(1);
        #pragma unroll
        for (int ks = 0; ks < 4; ++ks)
            S = __builtin_amdgcn_mfma_f32_32x32x16_bf16(kf[ks], Qf[ks], S, 0, 0, 0);
        __builtin_amdgcn_s_setprio(0);
        if (t < 31) loadK(t + 1);

        // ---- no-max softmax (masked keys give p = 1 exactly) -----------
        float pp[16];
        #pragma unroll
        for (int r = 0; r < 16; ++r)
            pp[r] = exp2f(S[r] * 0.18033688011112042f);
        l_acc += (((pp[0] + pp[1]) + (pp[2] + pp[3]))
                + ((pp[4] + pp[5]) + (pp[6] + pp[7])))
               + (((pp[8] + pp[9]) + (pp[10] + pp[11]))
                + ((pp[12] + pp[13]) + (pp[14] + pp[15])));
        u32 W[8];
        #pragma unroll
        for (int c = 0; c < 4; ++c) {
            W[2 * c + 0] = cvtpk(pp[4 * c + 0], pp[4 * c + 1]);
            W[2 * c + 1] = cvtpk(pp[4 * c + 2], pp[4 * c + 3]);
        }
        asm("v_permlane32_swap_b32 %0, %1" : "+v"(W[0]), "+v"(W[2]));
        asm("v_permlane32_swap_b32 %0, %1" : "+v"(W[1]), "+v"(W[3]));
        asm("v_permlane32_swap_b32 %0, %1" : "+v"(W[4]), "+v"(W[6]));
        asm("v_permlane32_swap_b32 %0, %1" : "+v"(W[5]), "+v"(W[7]));
        s16x8 pa[2];
        {
            u32x4 lo, hi;
            lo[0] = W[0]; lo[1] = W[1]; lo[2] = W[2]; lo[3] = W[3];
            hi[0] = W[4]; hi[1] = W[5]; hi[2] = W[6]; hi[3] = W[7];
            pa[0] = __builtin_bit_cast(s16x8, lo);
            pa[1] = __builtin_bit_cast(s16x8, hi);
        }

        // ---- PV: O[q][w] += P x V --------------------------------------
        __builtin_amdgcn_s_setprio(1);
        #pragma unroll
        for (int wt = 0; wt < 2; ++wt)
            #pragma unroll
            for (int t2 = 0; t2 < 2; ++t2)
                O[wt] = __builtin_amdgcn_mfma_f32_32x32x16_bf16(
                    pa[t2], vf[wt * 2 + t2], O[wt], 0, 0, 0);
        __builtin_amdgcn_s_setprio(0);
        if (t < 31) loadV(t + 1);
    }

    // ---- l reduction: h32 pair then cross-wave via LDS ------------------
    float ls = l_acc + __shfl_xor(l_acc, 32);
    if (lane < 32) lw[qg][kq][l31] = ls;

    // ---- O reduction across the 4 kq waves ------------------------------
    const float cnt = (float)cntb[b];
    const int grp = tid >> 8;
    const int tt  = tid & 255;
    const int qr  = tt >> 3;
    const int w8  = (tt & 7) * 4;
    #pragma unroll
    for (int wt = 0; wt < 2; ++wt) {
        __syncthreads();
        #pragma unroll
        for (int r = 0; r < 16; ++r)
            Ored[qg][kq][(r & 3) + 8 * (r >> 2) + 4 * h32][l31] = O[wt][r];
        __syncthreads();
        float4 s0 = *reinterpret_cast<const float4*>(&Ored[grp][0][qr][w8]);
        float4 s1 = *reinterpret_cast<const float4*>(&Ored[grp][1][qr][w8]);
        float4 s2 = *reinterpret_cast<const float4*>(&Ored[grp][2][qr][w8]);
        float4 s3 = *reinterpret_cast<const float4*>(&Ored[grp][3][qr][w8]);
        float l = (lw[grp][0][qr] + lw[grp][1][qr]
                 + lw[grp][2][qr] + lw[grp][3][qr]) - cnt;
        float inv = 1.f / l;
        int qglob = qt * 64 + grp * 32 + qr;
        float4 o;
        o.x = (s0.x + s1.x + s2.x + s3.x) * inv;
        o.y = (s0.y + s1.y + s2.y + s3.y) * inv;
        o.z = (s0.z + s1.z + s2.z + s3.z) * inv;
        o.w = (s0.w + s1.w + s2.w + s3.w) * inv;
        *reinterpret_cast<float4*>(
            &out[((size_t)b * 2048 + qglob) * 512 + hh * 64 + wt * 32 + w8]) = o;
    }
}

extern "C" void kernel_launch(void* const* d_in, const int* in_sizes, int n_in,
                              void* d_out, int out_size, void* d_ws, size_t ws_size,
                              hipStream_t stream)
{
    const float* q    = (const float*)d_in[0];
    const float* k    = (const float*)d_in[1];
    const int*   mask = (const int*)  d_in[2];
    const float* Wq   = (const float*)d_in[3];
    const float* bq   = (const float*)d_in[4];
    const float* Wk   = (const float*)d_in[5];
    const float* bk   = (const float*)d_in[6];
    const float* Wv   = (const float*)d_in[7];
    const float* bv   = (const float*)d_in[8];
    float* out = (float*)d_out;

    unsigned short* p = (unsigned short*)d_ws;
    unsigned short* qh  = p; p += (size_t)2 * 8 * 2048 * 64;   // 4MB
    unsigned short* kh  = p; p += (size_t)2 * 8 * 4096 * 64;   // 8MB
    unsigned short* vt  = p; p += (size_t)2 * 8 * 4096 * 64;   // 8MB
    unsigned short* qbf = p; p += (size_t)2 * 2048 * 512;      // 4MB
    unsigned short* kbf = p; p += (size_t)2 * 4096 * 512;      // 8MB
    unsigned short* wtq = p; p += 512 * 512;
    unsigned short* wtk = p; p += 512 * 512;
    unsigned short* wtv = p; p += 512 * 512;
    int* cntb = (int*)p;                                        // 2 ints

    dim3 blk(256);
    prep<<<dim3(3266), blk, 0, stream>>>(q, k, Wq, Wk, Wv, mask,
                                         qbf, kbf, wtq, wtk, wtv, cntb);
    proj3<<<dim3(1280), blk, 0, stream>>>(qbf, kbf, wtq, wtk, wtv,
                                          bq, bk, bv, mask, qh, kh, vt);
    attn9<<<dim3(512), dim3(512), 0, stream>>>(qh, kh, vt, cntb, out);
}

// Round 13
// 117.351 us; speedup vs baseline: 1.3573x; 1.3573x over previous
//
#include <hip/hip_runtime.h>
#include <hip/hip_bf16.h>

// R13 = R12 with the workspace-aliasing bug fixed: cntb was placed at
// alias+13.5MB, inside OP's 16MB span -> attn10 partial-O writes clobbered
// the masked-key counts before combine read them (absmax 5.2e-2 = cnt/l).
// cntb now lives past the end of OP+lp. Attention structure unchanged:
// R6's proven 8-wave 32k x 64q shape (64-reg O accumulator prevents the
// 64-VGPR squeeze of R7/R9-R11) + split-KV x2 -> grid 512 = 2 blocks/CU.

typedef short  s16x8 __attribute__((ext_vector_type(8)));
typedef short  s16x4 __attribute__((ext_vector_type(4)));
typedef float  f32x4 __attribute__((ext_vector_type(4)));
typedef float  f32x16 __attribute__((ext_vector_type(16)));
typedef unsigned int u32;
typedef unsigned int u32x4 __attribute__((ext_vector_type(4)));

__device__ __forceinline__ unsigned short f2bf(float x) {
    return __builtin_bit_cast(unsigned short, __float2bfloat16(x));
}
__device__ __forceinline__ void gload16(const void* g, void* lds) {
    __builtin_amdgcn_global_load_lds(
        (const __attribute__((address_space(1))) unsigned int*)g,
        (__attribute__((address_space(3))) unsigned int*)lds, 16, 0, 0);
}
__device__ __forceinline__ u32 cvtpk(float lo, float hi) {
    u32 r;
    asm("v_cvt_pk_bf16_f32 %0, %1, %2" : "=v"(r) : "v"(lo), "v"(hi));
    return r;
}

// ---------------- prep: cast q,k; transpose/cast W; count masked keys ------
__global__ __launch_bounds__(256) void prep(
    const float* __restrict__ q, const float* __restrict__ k,
    const float* __restrict__ Wq, const float* __restrict__ Wk,
    const float* __restrict__ Wv, const int* __restrict__ mask,
    unsigned short* __restrict__ qbf, unsigned short* __restrict__ kbf,
    unsigned short* __restrict__ wtq, unsigned short* __restrict__ wtk,
    unsigned short* __restrict__ wtv, int* __restrict__ cntb)
{
    __shared__ float T[64][65];
    const int bid = blockIdx.x;
    const int tid = threadIdx.x;
    if (bid < 3072) {
        const float* src = bid < 1024 ? q : k;
        unsigned short* dst = bid < 1024 ? qbf : kbf;
        int i = (bid < 1024 ? bid : bid - 1024) * 256 + tid;
        float4 a = reinterpret_cast<const float4*>(src)[2 * i];
        float4 b = reinterpret_cast<const float4*>(src)[2 * i + 1];
        s16x8 o;
        o[0] = (short)f2bf(a.x); o[1] = (short)f2bf(a.y);
        o[2] = (short)f2bf(a.z); o[3] = (short)f2bf(a.w);
        o[4] = (short)f2bf(b.x); o[5] = (short)f2bf(b.y);
        o[6] = (short)f2bf(b.z); o[7] = (short)f2bf(b.w);
        reinterpret_cast<s16x8*>(dst)[i] = o;
    } else if (bid < 3264) {
        int t = bid - 3072;
        int z = t >> 6;
        int tt = t & 63;
        const float* W = z == 0 ? Wq : z == 1 ? Wk : Wv;
        unsigned short* D = z == 0 ? wtq : z == 1 ? wtk : wtv;
        const int k0 = (tt >> 3) * 64, n0 = (tt & 7) * 64;
        const int r = tid >> 2, cq = tid & 3;
        #pragma unroll
        for (int p = 0; p < 4; ++p) {
            int c = (cq + 4 * p) * 4;
            float4 v = *reinterpret_cast<const float4*>(
                &W[(size_t)(k0 + r) * 512 + n0 + c]);
            T[c + 0][r] = v.x; T[c + 1][r] = v.y;
            T[c + 2][r] = v.z; T[c + 3][r] = v.w;
        }
        __syncthreads();
        #pragma unroll
        for (int p = 0; p < 4; ++p) {
            int kc = (cq + 4 * p) * 4;
            s16x4 o;
            o[0] = (short)f2bf(T[r][kc + 0]);
            o[1] = (short)f2bf(T[r][kc + 1]);
            o[2] = (short)f2bf(T[r][kc + 2]);
            o[3] = (short)f2bf(T[r][kc + 3]);
            *reinterpret_cast<s16x4*>(&D[(size_t)(n0 + r) * 512 + k0 + kc]) = o;
        }
    } else {
        // blocks 3264/3265: per-batch masked-key count (deterministic)
        __shared__ int red[4];
        int b = bid - 3264;
        int base = b * 4096 + tid * 16;
        int s = 0;
        #pragma unroll
        for (int p = 0; p < 4; ++p) {
            int4 m = *reinterpret_cast<const int4*>(&mask[base + 4 * p]);
            s += m.x + m.y + m.z + m.w;
        }
        #pragma unroll
        for (int off = 1; off < 64; off <<= 1)
            s += __shfl_xor(s, off);
        if ((tid & 63) == 0) red[tid >> 6] = s;
        __syncthreads();
        if (tid == 0)
            cntb[b] = 4096 - (red[0] + red[1] + red[2] + red[3]);
    }
}

// ---------------- fused 3-way projection GEMM, bf16 MFMA, 2-phase ----------
// mflag: 0 = none (Q), 1 = zero masked rows (K), 2 = zero masked cols (V^T)
__global__ __launch_bounds__(256) void proj3(
    const unsigned short* __restrict__ qbf, const unsigned short* __restrict__ kbf,
    const unsigned short* __restrict__ wtq, const unsigned short* __restrict__ wtk,
    const unsigned short* __restrict__ wtv,
    const float* __restrict__ bq, const float* __restrict__ bk,
    const float* __restrict__ bv, const int* __restrict__ mask,
    unsigned short* __restrict__ qh, unsigned short* __restrict__ kh,
    unsigned short* __restrict__ vt)
{
    __shared__ unsigned short As[2][128 * 64];
    __shared__ unsigned short Bs[2][64 * 64];

    const int tid  = threadIdx.x;
    const int wv   = tid >> 6;
    const int lane = tid & 63;
    const int g    = lane >> 4;
    const int ln   = lane & 15;
    const int swz  = (ln & 7) << 3;

    const int id = blockIdx.x;
    const unsigned short *A, *Wt;
    const float* bias;
    unsigned short* dst;
    int S, trans, nb, mb, mflag;
    if (id < 256)      { A = qbf; Wt = wtq; bias = bq; dst = qh; S = 2048; trans = 0; mflag = 0; nb = id & 7;         mb = id >> 3; }
    else if (id < 768) { A = kbf; Wt = wtk; bias = bk; dst = kh; S = 4096; trans = 0; mflag = 1; nb = (id - 256) & 7; mb = (id - 256) >> 3; }
    else               { A = kbf; Wt = wtv; bias = bv; dst = vt; S = 4096; trans = 1; mflag = 2; nb = (id - 768) & 7; mb = (id - 768) >> 3; }
    const int m0 = mb * 128, n0 = nb * 64;

    f32x4 acc[4][2];
    #pragma unroll
    for (int i = 0; i < 4; ++i)
        #pragma unroll
        for (int j = 0; j < 2; ++j) acc[i][j] = (f32x4)0.f;

    auto stage = [&](int bufn, int k0) {
        #pragma unroll
        for (int p = 0; p < 4; ++p) {
            int slot = p * 256 + tid;
            int row = slot >> 3, cb = slot & 7;
            int cbp = cb ^ (row & 7);
            gload16(&A[(size_t)(m0 + row) * 512 + k0 + cbp * 8], &As[bufn][slot * 8]);
        }
        #pragma unroll
        for (int p = 0; p < 2; ++p) {
            int slot = p * 256 + tid;
            int row = slot >> 3, cb = slot & 7;
            int cbp = cb ^ (row & 7);
            gload16(&Wt[(size_t)(n0 + row) * 512 + k0 + cbp * 8], &Bs[bufn][slot * 8]);
        }
    };

    stage(0, 0);
    __syncthreads();
    int buf = 0;
    for (int kk = 0; kk < 8; ++kk) {
        if (kk < 7) stage(buf ^ 1, (kk + 1) * 64);
        #pragma unroll
        for (int ks = 0; ks < 2; ++ks) {
            s16x8 fa[2], fb[4];
            #pragma unroll
            for (int mi = 0; mi < 2; ++mi)
                fa[mi] = *reinterpret_cast<const s16x8*>(
                    &As[buf][((wv * 32 + 16 * mi + ln) * 64 + ks * 32 + g * 8) ^ swz]);
            #pragma unroll
            for (int nj = 0; nj < 4; ++nj)
                fb[nj] = *reinterpret_cast<const s16x8*>(
                    &Bs[buf][((16 * nj + ln) * 64 + ks * 32 + g * 8) ^ swz]);
            if (!trans) {
                #pragma unroll
                for (int mi = 0; mi < 2; ++mi)
                    #pragma unroll
                    for (int nj = 0; nj < 4; ++nj)
                        acc[nj][mi] = __builtin_amdgcn_mfma_f32_16x16x32_bf16(
                            fa[mi], fb[nj], acc[nj][mi], 0, 0, 0);
            } else {
                #pragma unroll
                for (int nj = 0; nj < 4; ++nj)
                    #pragma unroll
                    for (int mi = 0; mi < 2; ++mi)
                        acc[nj][mi] = __builtin_amdgcn_mfma_f32_16x16x32_bf16(
                            fb[nj], fa[mi], acc[nj][mi], 0, 0, 0);
            }
        }
        __syncthreads();
        buf ^= 1;
    }

    const int h    = nb;
    const int bidx = m0 / S;
    const int s0   = m0 - bidx * S;

    if (!trans) {
        float bvv[4];
        #pragma unroll
        for (int nj = 0; nj < 4; ++nj) bvv[nj] = bias[n0 + 16 * nj + ln];
        unsigned short* base = dst + (size_t)(bidx * 8 + h) * S * 64;
        #pragma unroll
        for (int mi = 0; mi < 2; ++mi)
            #pragma unroll
            for (int r = 0; r < 4; ++r) {
                int s = s0 + wv * 32 + 16 * mi + 4 * g + r;
                float fm = (mflag == 1) ? (float)mask[bidx * 4096 + s] : 1.f;
                #pragma unroll
                for (int nj = 0; nj < 4; ++nj)
                    base[(size_t)s * 64 + 16 * nj + ln] =
                        f2bf((acc[nj][mi][r] + bvv[nj]) * fm);
            }
    } else {
        float fmc[2];
        #pragma unroll
        for (int mi = 0; mi < 2; ++mi)
            fmc[mi] = (float)mask[bidx * 4096 + s0 + wv * 32 + 16 * mi + ln];
        unsigned short* base = dst + (size_t)(bidx * 8 + h) * 64 * (size_t)S;
        #pragma unroll
        for (int nj = 0; nj < 4; ++nj)
            #pragma unroll
            for (int r = 0; r < 4; ++r) {
                int w = 16 * nj + 4 * g + r;
                float bw = bias[n0 + w];
                #pragma unroll
                for (int mi = 0; mi < 2; ++mi)
                    base[(size_t)w * S + s0 + wv * 32 + 16 * mi + ln] =
                        f2bf((acc[nj][mi][r] + bw) * fmc[mi]);
            }
    }
}

// ------- attention: R6 structure + split-KV x2, partial outputs ------------
__global__ __launch_bounds__(512) void attn10(
    const unsigned short* __restrict__ qh,  // [B,8,2048,64] bf16
    const unsigned short* __restrict__ kh,  // [B,8,4096,64] bf16 (masked rows 0)
    const unsigned short* __restrict__ vt,  // [B,8,64,4096] bf16 (masked cols 0)
    float* __restrict__ OP,                 // [chunk 2][bh 16][q 2048][w 64]
    float* __restrict__ lp)                 // [chunk 2][bh 16][q 2048]
{
    __shared__ float Ored[2][4][32][36];    // [qg][kq][q32][w32+pad]
    __shared__ float lw[2][2][4][32];       // [qg][qt2][kq][q31]

    const int tid  = threadIdx.x;
    const int wid  = tid >> 6;
    const int kq   = wid & 3;       // key-quarter owner
    const int qg   = wid >> 2;      // q-half (64 rows)
    const int lane = tid & 63;
    const int l31  = lane & 31;
    const int h32  = lane >> 5;

    // XCD-clustered: 2 bh per XCD; per bh: 16 q-blocks x 2 chunks
    const int id    = blockIdx.x;
    const int xcd   = id & 7;
    const int j     = id >> 3;              // 0..63
    const int bh    = xcd * 2 + (j >> 5);
    const int qt    = (j & 31) >> 1;        // 0..15
    const int chunk = j & 1;
    const int kc0   = chunk * 2048;

    const unsigned short* Kp = kh + (size_t)bh * 4096 * 64
                               + (size_t)(kc0 + kq * 32 + l31) * 64 + h32 * 8;
    const unsigned short* Vp0 = vt + (size_t)bh * 64 * 4096
                               + (size_t)l31 * 4096 + kc0 + kq * 32 + h32 * 8;

    // Q fragments (B operand): col = l31, k = ks*16 + 8*h32 + j
    s16x8 Qf[2][4];
    {
        const unsigned short* Qb = qh + ((size_t)bh * 2048 + qt * 128 + qg * 64) * 64;
        #pragma unroll
        for (int qt2 = 0; qt2 < 2; ++qt2)
            #pragma unroll
            for (int ks = 0; ks < 4; ++ks)
                Qf[qt2][ks] = *reinterpret_cast<const s16x8*>(
                    &Qb[(size_t)(qt2 * 32 + l31) * 64 + ks * 16 + h32 * 8]);
    }

    f32x16 O[2][2];
    #pragma unroll
    for (int i = 0; i < 2; ++i)
        #pragma unroll
        for (int jj = 0; jj < 2; ++jj) O[i][jj] = (f32x16)0.f;
    float l_acc0 = 0.f, l_acc1 = 0.f;

    s16x8 kf[4], vf[4];

    auto loadK = [&](int t) {
        #pragma unroll
        for (int ks = 0; ks < 4; ++ks)
            kf[ks] = *reinterpret_cast<const s16x8*>(Kp + (size_t)t * 8192 + ks * 16);
    };
    auto loadV = [&](int t) {
        #pragma unroll
        for (int wt = 0; wt < 2; ++wt)
            #pragma unroll
            for (int t2 = 0; t2 < 2; ++t2)
                vf[wt * 2 + t2] = *reinterpret_cast<const s16x8*>(
                    Vp0 + (size_t)wt * 32 * 4096 + t * 128 + t2 * 16);
    };

    loadK(0); loadV(0);

    for (int t = 0; t < 16; ++t) {
        // ---- QK^T: S^T[32 keys][64 q] ----------------------------------
        f32x16 S[2];
        S[0] = (f32x16)0.f; S[1] = (f32x16)0.f;
        __builtin_amdgcn_s_setprio(1);
        #pragma unroll
        for (int ks = 0; ks < 4; ++ks) {
            S[0] = __builtin_amdgcn_mfma_f32_32x32x16_bf16(kf[ks], Qf[0][ks], S[0], 0, 0, 0);
            S[1] = __builtin_amdgcn_mfma_f32_32x32x16_bf16(kf[ks], Qf[1][ks], S[1], 0, 0, 0);
        }
        __builtin_amdgcn_s_setprio(0);
        if (t < 15) loadK(t + 1);

        // ---- no-max softmax + pack P to bf16 A-frags -------------------
        s16x8 pa[2][2];
        #pragma unroll
        for (int qt2 = 0; qt2 < 2; ++qt2) {
            float pp[16];
            #pragma unroll
            for (int r = 0; r < 16; ++r)
                pp[r] = exp2f(S[qt2][r] * 0.18033688011112042f);
            float ls = (((pp[0] + pp[1]) + (pp[2] + pp[3]))
                     + ((pp[4] + pp[5]) + (pp[6] + pp[7])))
                     + (((pp[8] + pp[9]) + (pp[10] + pp[11]))
                     + ((pp[12] + pp[13]) + (pp[14] + pp[15])));
            if (qt2 == 0) l_acc0 += ls; else l_acc1 += ls;
            u32 W[8];
            #pragma unroll
            for (int c = 0; c < 4; ++c) {
                W[2 * c + 0] = cvtpk(pp[4 * c + 0], pp[4 * c + 1]);
                W[2 * c + 1] = cvtpk(pp[4 * c + 2], pp[4 * c + 3]);
            }
            asm("v_permlane32_swap_b32 %0, %1" : "+v"(W[0]), "+v"(W[2]));
            asm("v_permlane32_swap_b32 %0, %1" : "+v"(W[1]), "+v"(W[3]));
            asm("v_permlane32_swap_b32 %0, %1" : "+v"(W[4]), "+v"(W[6]));
            asm("v_permlane32_swap_b32 %0, %1" : "+v"(W[5]), "+v"(W[7]));
            u32x4 lo, hi;
            lo[0] = W[0]; lo[1] = W[1]; lo[2] = W[2]; lo[3] = W[3];
            hi[0] = W[4]; hi[1] = W[5]; hi[2] = W[6]; hi[3] = W[7];
            pa[qt2][0] = __builtin_bit_cast(s16x8, lo);
            pa[qt2][1] = __builtin_bit_cast(s16x8, hi);
        }

        // ---- PV: O[q][w] += P x V --------------------------------------
        __builtin_amdgcn_s_setprio(1);
        #pragma unroll
        for (int qt2 = 0; qt2 < 2; ++qt2)
            #pragma unroll
            for (int wt = 0; wt < 2; ++wt)
                #pragma unroll
                for (int t2 = 0; t2 < 2; ++t2)
                    O[qt2][wt] = __builtin_amdgcn_mfma_f32_32x32x16_bf16(
                        pa[qt2][t2], vf[wt * 2 + t2], O[qt2][wt], 0, 0, 0);
        __builtin_amdgcn_s_setprio(0);
        if (t < 15) loadV(t + 1);
    }

    // ---- l reduction: h32 pair then cross-wave via LDS ------------------
    float ls0 = l_acc0 + __shfl_xor(l_acc0, 32);
    float ls1 = l_acc1 + __shfl_xor(l_acc1, 32);
    if (lane < 32) {
        lw[qg][0][kq][l31] = ls0;
        lw[qg][1][kq][l31] = ls1;
    }

    // ---- O reduction across the 4 kq waves; write partials --------------
    const int grp = tid >> 8;          // q-group of this thread (0/1)
    const int tt  = tid & 255;
    const int qr  = tt >> 3;           // 0..31
    const int w8  = (tt & 7) * 4;      // 0..28
    const size_t pbase = (size_t)(chunk * 16 + bh) * 2048;
    #pragma unroll
    for (int qt2 = 0; qt2 < 2; ++qt2)
        #pragma unroll
        for (int wt = 0; wt < 2; ++wt) {
            __syncthreads();
            f32x16 oo = O[qt2][wt];
            #pragma unroll
            for (int r = 0; r < 16; ++r)
                Ored[qg][kq][(r & 3) + 8 * (r >> 2) + 4 * h32][l31] = oo[r];
            __syncthreads();
            float4 s  = *reinterpret_cast<const float4*>(&Ored[grp][0][qr][w8]);
            float4 s1 = *reinterpret_cast<const float4*>(&Ored[grp][1][qr][w8]);
            float4 s2 = *reinterpret_cast<const float4*>(&Ored[grp][2][qr][w8]);
            float4 s3 = *reinterpret_cast<const float4*>(&Ored[grp][3][qr][w8]);
            s.x += s1.x + s2.x + s3.x;
            s.y += s1.y + s2.y + s3.y;
            s.z += s1.z + s2.z + s3.z;
            s.w += s1.w + s2.w + s3.w;
            int qglob = qt * 128 + grp * 64 + qt2 * 32 + qr;
            *reinterpret_cast<float4*>(
                &OP[(pbase + qglob) * 64 + wt * 32 + w8]) = s;
            if (wt == 0 && w8 == 0) {
                float l = lw[grp][qt2][0][qr] + lw[grp][qt2][1][qr]
                        + lw[grp][qt2][2][qr] + lw[grp][qt2][3][qr];
                lp[pbase + qglob] = l;
            }
        }
}

// ---------------- combine: out = (O0+O1)/(l0+l1-cnt) -----------------------
__global__ __launch_bounds__(256) void combine(
    const float* __restrict__ OP, const float* __restrict__ lp,
    const int* __restrict__ cntb, float* __restrict__ out)
{
    int id = blockIdx.x * 256 + threadIdx.x;   // 0..524287
    int w4 = id & 15;
    int h  = (id >> 4) & 7;
    int q  = (id >> 7) & 2047;
    int b  = id >> 18;
    int bh = b * 8 + h;
    size_t i0 = (size_t)bh * 2048 + q;
    const size_t C1O = (size_t)16 * 2048 * 64;
    const size_t C1L = (size_t)16 * 2048;
    float4 o0 = *reinterpret_cast<const float4*>(&OP[i0 * 64 + w4 * 4]);
    float4 o1 = *reinterpret_cast<const float4*>(&OP[C1O + i0 * 64 + w4 * 4]);
    float inv = 1.f / (lp[i0] + lp[C1L + i0] - (float)cntb[b]);
    float4 o;
    o.x = (o0.x + o1.x) * inv;
    o.y = (o0.y + o1.y) * inv;
    o.z = (o0.z + o1.z) * inv;
    o.w = (o0.w + o1.w) * inv;
    *reinterpret_cast<float4*>(
        &out[((size_t)b * 2048 + q) * 512 + h * 64 + w4 * 4]) = o;
}

extern "C" void kernel_launch(void* const* d_in, const int* in_sizes, int n_in,
                              void* d_out, int out_size, void* d_ws, size_t ws_size,
                              hipStream_t stream)
{
    const float* q    = (const float*)d_in[0];
    const float* k    = (const float*)d_in[1];
    const int*   mask = (const int*)  d_in[2];
    const float* Wq   = (const float*)d_in[3];
    const float* bq   = (const float*)d_in[4];
    const float* Wk   = (const float*)d_in[5];
    const float* bk   = (const float*)d_in[6];
    const float* Wv   = (const float*)d_in[7];
    const float* bv   = (const float*)d_in[8];
    float* out = (float*)d_out;

    unsigned short* p = (unsigned short*)d_ws;
    unsigned short* qh  = p; p += (size_t)2 * 8 * 2048 * 64;   // 4MB
    unsigned short* kh  = p; p += (size_t)2 * 8 * 4096 * 64;   // 8MB
    unsigned short* vt  = p; p += (size_t)2 * 8 * 4096 * 64;   // 8MB
    // dual-use: {qbf,kbf,wt*} (13.5MB) for proj, then {OP,lp} (16.25MB)
    // for attention partials. cntb lives BEYOND the union of both uses.
    unsigned short* alias = p;
    unsigned short* qbf = alias;
    unsigned short* kbf = qbf + (size_t)2 * 2048 * 512;        // +4MB
    unsigned short* wtq = kbf + (size_t)2 * 4096 * 512;        // +8MB
    unsigned short* wtk = wtq + 512 * 512;
    unsigned short* wtv = wtk + 512 * 512;
    float* OP = (float*)alias;                                 // 16MB
    float* lp = OP + (size_t)2 * 16 * 2048 * 64;               // +256KB
    int* cntb = (int*)(lp + (size_t)2 * 16 * 2048);            // past OP+lp AND wt region

    dim3 blk(256);
    prep<<<dim3(3266), blk, 0, stream>>>(q, k, Wq, Wk, Wv, mask,
                                         qbf, kbf, wtq, wtk, wtv, cntb);
    proj3<<<dim3(1280), blk, 0, stream>>>(qbf, kbf, wtq, wtk, wtv,
                                          bq, bk, bv, mask, qh, kh, vt);
    attn10<<<dim3(512), dim3(512), 0, stream>>>(qh, kh, vt, OP, lp);
    combine<<<dim3(2048), blk, 0, stream>>>(OP, lp, cntb, out);
}

// Round 16
// 106.379 us; speedup vs baseline: 1.4973x; 1.1031x over previous
//
#include <hip/hip_runtime.h>
#include <hip/hip_bf16.h>

// R16 = R14 resubmitted (3rd attempt; R14/R15 hit broker-level infra flakes
// on pod odd-lone-also-lake before any test ran). Consolidation: non-split
// attention (grid 256, 32 KV-tiles/block) writing out directly with
// /(l - cnt) -> no combine kernel, no workspace aliasing (R12 bug class
// eliminated). Softmax scale log2(e)/8 folded into the Q projection
// epilogue -> attn inner loop is exp2f(S) with no mul. Attention core =
// R6/R13's proven 8-wave 32k x 64q, 64-reg O accumulator (forces VGPR~104,
// prevents the 64-VGPR squeeze of R7/R9-R11).

typedef short  s16x8 __attribute__((ext_vector_type(8)));
typedef short  s16x4 __attribute__((ext_vector_type(4)));
typedef float  f32x4 __attribute__((ext_vector_type(4)));
typedef float  f32x16 __attribute__((ext_vector_type(16)));
typedef unsigned int u32;
typedef unsigned int u32x4 __attribute__((ext_vector_type(4)));

__device__ __forceinline__ unsigned short f2bf(float x) {
    return __builtin_bit_cast(unsigned short, __float2bfloat16(x));
}
__device__ __forceinline__ void gload16(const void* g, void* lds) {
    __builtin_amdgcn_global_load_lds(
        (const __attribute__((address_space(1))) unsigned int*)g,
        (__attribute__((address_space(3))) unsigned int*)lds, 16, 0, 0);
}
__device__ __forceinline__ u32 cvtpk(float lo, float hi) {
    u32 r;
    asm("v_cvt_pk_bf16_f32 %0, %1, %2" : "=v"(r) : "v"(lo), "v"(hi));
    return r;
}

// ---------------- prep: cast q,k; transpose/cast W; count masked keys ------
__global__ __launch_bounds__(256) void prep(
    const float* __restrict__ q, const float* __restrict__ k,
    const float* __restrict__ Wq, const float* __restrict__ Wk,
    const float* __restrict__ Wv, const int* __restrict__ mask,
    unsigned short* __restrict__ qbf, unsigned short* __restrict__ kbf,
    unsigned short* __restrict__ wtq, unsigned short* __restrict__ wtk,
    unsigned short* __restrict__ wtv, int* __restrict__ cntb)
{
    __shared__ float T[64][65];
    const int bid = blockIdx.x;
    const int tid = threadIdx.x;
    if (bid < 3072) {
        const float* src = bid < 1024 ? q : k;
        unsigned short* dst = bid < 1024 ? qbf : kbf;
        int i = (bid < 1024 ? bid : bid - 1024) * 256 + tid;
        float4 a = reinterpret_cast<const float4*>(src)[2 * i];
        float4 b = reinterpret_cast<const float4*>(src)[2 * i + 1];
        s16x8 o;
        o[0] = (short)f2bf(a.x); o[1] = (short)f2bf(a.y);
        o[2] = (short)f2bf(a.z); o[3] = (short)f2bf(a.w);
        o[4] = (short)f2bf(b.x); o[5] = (short)f2bf(b.y);
        o[6] = (short)f2bf(b.z); o[7] = (short)f2bf(b.w);
        reinterpret_cast<s16x8*>(dst)[i] = o;
    } else if (bid < 3264) {
        int t = bid - 3072;
        int z = t >> 6;
        int tt = t & 63;
        const float* W = z == 0 ? Wq : z == 1 ? Wk : Wv;
        unsigned short* D = z == 0 ? wtq : z == 1 ? wtk : wtv;
        const int k0 = (tt >> 3) * 64, n0 = (tt & 7) * 64;
        const int r = tid >> 2, cq = tid & 3;
        #pragma unroll
        for (int p = 0; p < 4; ++p) {
            int c = (cq + 4 * p) * 4;
            float4 v = *reinterpret_cast<const float4*>(
                &W[(size_t)(k0 + r) * 512 + n0 + c]);
            T[c + 0][r] = v.x; T[c + 1][r] = v.y;
            T[c + 2][r] = v.z; T[c + 3][r] = v.w;
        }
        __syncthreads();
        #pragma unroll
        for (int p = 0; p < 4; ++p) {
            int kc = (cq + 4 * p) * 4;
            s16x4 o;
            o[0] = (short)f2bf(T[r][kc + 0]);
            o[1] = (short)f2bf(T[r][kc + 1]);
            o[2] = (short)f2bf(T[r][kc + 2]);
            o[3] = (short)f2bf(T[r][kc + 3]);
            *reinterpret_cast<s16x4*>(&D[(size_t)(n0 + r) * 512 + k0 + kc]) = o;
        }
    } else {
        // blocks 3264/3265: per-batch masked-key count (deterministic)
        __shared__ int red[4];
        int b = bid - 3264;
        int base = b * 4096 + tid * 16;
        int s = 0;
        #pragma unroll
        for (int p = 0; p < 4; ++p) {
            int4 m = *reinterpret_cast<const int4*>(&mask[base + 4 * p]);
            s += m.x + m.y + m.z + m.w;
        }
        #pragma unroll
        for (int off = 1; off < 64; off <<= 1)
            s += __shfl_xor(s, off);
        if ((tid & 63) == 0) red[tid >> 6] = s;
        __syncthreads();
        if (tid == 0)
            cntb[b] = 4096 - (red[0] + red[1] + red[2] + red[3]);
    }
}

// ---------------- fused 3-way projection GEMM, bf16 MFMA, 2-phase ----------
// mflag: 0 = Q (scale by log2e/8), 1 = K (zero masked rows), 2 = V^T (zero
// masked cols).
__global__ __launch_bounds__(256) void proj3(
    const unsigned short* __restrict__ qbf, const unsigned short* __restrict__ kbf,
    const unsigned short* __restrict__ wtq, const unsigned short* __restrict__ wtk,
    const unsigned short* __restrict__ wtv,
    const float* __restrict__ bq, const float* __restrict__ bk,
    const float* __restrict__ bv, const int* __restrict__ mask,
    unsigned short* __restrict__ qh, unsigned short* __restrict__ kh,
    unsigned short* __restrict__ vt)
{
    __shared__ unsigned short As[2][128 * 64];
    __shared__ unsigned short Bs[2][64 * 64];

    const int tid  = threadIdx.x;
    const int wv   = tid >> 6;
    const int lane = tid & 63;
    const int g    = lane >> 4;
    const int ln   = lane & 15;
    const int swz  = (ln & 7) << 3;

    const int id = blockIdx.x;
    const unsigned short *A, *Wt;
    const float* bias;
    unsigned short* dst;
    int S, trans, nb, mb, mflag;
    if (id < 256)      { A = qbf; Wt = wtq; bias = bq; dst = qh; S = 2048; trans = 0; mflag = 0; nb = id & 7;         mb = id >> 3; }
    else if (id < 768) { A = kbf; Wt = wtk; bias = bk; dst = kh; S = 4096; trans = 0; mflag = 1; nb = (id - 256) & 7; mb = (id - 256) >> 3; }
    else               { A = kbf; Wt = wtv; bias = bv; dst = vt; S = 4096; trans = 1; mflag = 2; nb = (id - 768) & 7; mb = (id - 768) >> 3; }
    const int m0 = mb * 128, n0 = nb * 64;
    const float scl = (mflag == 0) ? 0.18033688011112042f : 1.f;

    f32x4 acc[4][2];
    #pragma unroll
    for (int i = 0; i < 4; ++i)
        #pragma unroll
        for (int j = 0; j < 2; ++j) acc[i][j] = (f32x4)0.f;

    auto stage = [&](int bufn, int k0) {
        #pragma unroll
        for (int p = 0; p < 4; ++p) {
            int slot = p * 256 + tid;
            int row = slot >> 3, cb = slot & 7;
            int cbp = cb ^ (row & 7);
            gload16(&A[(size_t)(m0 + row) * 512 + k0 + cbp * 8], &As[bufn][slot * 8]);
        }
        #pragma unroll
        for (int p = 0; p < 2; ++p) {
            int slot = p * 256 + tid;
            int row = slot >> 3, cb = slot & 7;
            int cbp = cb ^ (row & 7);
            gload16(&Wt[(size_t)(n0 + row) * 512 + k0 + cbp * 8], &Bs[bufn][slot * 8]);
        }
    };

    stage(0, 0);
    __syncthreads();
    int buf = 0;
    for (int kk = 0; kk < 8; ++kk) {
        if (kk < 7) stage(buf ^ 1, (kk + 1) * 64);
        #pragma unroll
        for (int ks = 0; ks < 2; ++ks) {
            s16x8 fa[2], fb[4];
            #pragma unroll
            for (int mi = 0; mi < 2; ++mi)
                fa[mi] = *reinterpret_cast<const s16x8*>(
                    &As[buf][((wv * 32 + 16 * mi + ln) * 64 + ks * 32 + g * 8) ^ swz]);
            #pragma unroll
            for (int nj = 0; nj < 4; ++nj)
                fb[nj] = *reinterpret_cast<const s16x8*>(
                    &Bs[buf][((16 * nj + ln) * 64 + ks * 32 + g * 8) ^ swz]);
            if (!trans) {
                #pragma unroll
                for (int mi = 0; mi < 2; ++mi)
                    #pragma unroll
                    for (int nj = 0; nj < 4; ++nj)
                        acc[nj][mi] = __builtin_amdgcn_mfma_f32_16x16x32_bf16(
                            fa[mi], fb[nj], acc[nj][mi], 0, 0, 0);
            } else {
                #pragma unroll
                for (int nj = 0; nj < 4; ++nj)
                    #pragma unroll
                    for (int mi = 0; mi < 2; ++mi)
                        acc[nj][mi] = __builtin_amdgcn_mfma_f32_16x16x32_bf16(
                            fb[nj], fa[mi], acc[nj][mi], 0, 0, 0);
            }
        }
        __syncthreads();
        buf ^= 1;
    }

    const int h    = nb;
    const int bidx = m0 / S;
    const int s0   = m0 - bidx * S;

    if (!trans) {
        float bvv[4];
        #pragma unroll
        for (int nj = 0; nj < 4; ++nj) bvv[nj] = bias[n0 + 16 * nj + ln];
        unsigned short* base = dst + (size_t)(bidx * 8 + h) * S * 64;
        #pragma unroll
        for (int mi = 0; mi < 2; ++mi)
            #pragma unroll
            for (int r = 0; r < 4; ++r) {
                int s = s0 + wv * 32 + 16 * mi + 4 * g + r;
                float fm = (mflag == 1) ? (float)mask[bidx * 4096 + s] : 1.f;
                float fs = fm * scl;
                #pragma unroll
                for (int nj = 0; nj < 4; ++nj)
                    base[(size_t)s * 64 + 16 * nj + ln] =
                        f2bf((acc[nj][mi][r] + bvv[nj]) * fs);
            }
    } else {
        float fmc[2];
        #pragma unroll
        for (int mi = 0; mi < 2; ++mi)
            fmc[mi] = (float)mask[bidx * 4096 + s0 + wv * 32 + 16 * mi + ln];
        unsigned short* base = dst + (size_t)(bidx * 8 + h) * 64 * (size_t)S;
        #pragma unroll
        for (int nj = 0; nj < 4; ++nj)
            #pragma unroll
            for (int r = 0; r < 4; ++r) {
                int w = 16 * nj + 4 * g + r;
                float bw = bias[n0 + w];
                #pragma unroll
                for (int mi = 0; mi < 2; ++mi)
                    base[(size_t)w * S + s0 + wv * 32 + 16 * mi + ln] =
                        f2bf((acc[nj][mi][r] + bw) * fmc[mi]);
            }
    }
}

// ------- attention: R6 structure, non-split, direct output -----------------
__global__ __launch_bounds__(512) void attn11(
    const unsigned short* __restrict__ qh,  // [B,8,2048,64] bf16 (pre-scaled)
    const unsigned short* __restrict__ kh,  // [B,8,4096,64] bf16 (masked rows 0)
    const unsigned short* __restrict__ vt,  // [B,8,64,4096] bf16 (masked cols 0)
    const int* __restrict__ cntb,           // [B] masked-key counts
    float* __restrict__ out)                // [B,2048,512]
{
    __shared__ float Ored[2][4][32][36];    // [qg][kq][q32][w32+pad]
    __shared__ float lw[2][2][4][32];       // [qg][qt2][kq][q31]

    const int tid  = threadIdx.x;
    const int wid  = tid >> 6;
    const int kq   = wid & 3;       // key-quarter owner
    const int qg   = wid >> 2;      // q-half (64 rows)
    const int lane = tid & 63;
    const int l31  = lane & 31;
    const int h32  = lane >> 5;

    // XCD-clustered: 2 bh per XCD; per bh: 16 q-blocks of 128 rows
    const int id  = blockIdx.x;
    const int xcd = id & 7;
    const int j   = id >> 3;               // 0..31
    const int bh  = xcd * 2 + (j >> 4);
    const int qt  = j & 15;
    const int b   = bh >> 3;
    const int hh  = bh & 7;

    const unsigned short* Kp = kh + (size_t)bh * 4096 * 64
                               + (size_t)(kq * 32 + l31) * 64 + h32 * 8;
    const unsigned short* Vp0 = vt + (size_t)bh * 64 * 4096
                               + (size_t)l31 * 4096 + kq * 32 + h32 * 8;

    // Q fragments (B operand): col = l31, k = ks*16 + 8*h32 + j
    s16x8 Qf[2][4];
    {
        const unsigned short* Qb = qh + ((size_t)bh * 2048 + qt * 128 + qg * 64) * 64;
        #pragma unroll
        for (int qt2 = 0; qt2 < 2; ++qt2)
            #pragma unroll
            for (int ks = 0; ks < 4; ++ks)
                Qf[qt2][ks] = *reinterpret_cast<const s16x8*>(
                    &Qb[(size_t)(qt2 * 32 + l31) * 64 + ks * 16 + h32 * 8]);
    }

    f32x16 O[2][2];
    #pragma unroll
    for (int i = 0; i < 2; ++i)
        #pragma unroll
        for (int jj = 0; jj < 2; ++jj) O[i][jj] = (f32x16)0.f;
    float l_acc0 = 0.f, l_acc1 = 0.f;

    s16x8 kf[4], vf[4];

    auto loadK = [&](int t) {
        #pragma unroll
        for (int ks = 0; ks < 4; ++ks)
            kf[ks] = *reinterpret_cast<const s16x8*>(Kp + (size_t)t * 8192 + ks * 16);
    };
    auto loadV = [&](int t) {
        #pragma unroll
        for (int wt = 0; wt < 2; ++wt)
            #pragma unroll
            for (int t2 = 0; t2 < 2; ++t2)
                vf[wt * 2 + t2] = *reinterpret_cast<const s16x8*>(
                    Vp0 + (size_t)wt * 32 * 4096 + t * 128 + t2 * 16);
    };

    loadK(0); loadV(0);

    for (int t = 0; t < 32; ++t) {
        // ---- QK^T: S^T[32 keys][64 q] (S pre-scaled via Q) -------------
        f32x16 S[2];
        S[0] = (f32x16)0.f; S[1] = (f32x16)0.f;
        __builtin_amdgcn_s_setprio(1);
        #pragma unroll
        for (int ks = 0; ks < 4; ++ks) {
            S[0] = __builtin_amdgcn_mfma_f32_32x32x16_bf16(kf[ks], Qf[0][ks], S[0], 0, 0, 0);
            S[1] = __builtin_amdgcn_mfma_f32_32x32x16_bf16(kf[ks], Qf[1][ks], S[1], 0, 0, 0);
        }
        __builtin_amdgcn_s_setprio(0);
        if (t < 31) loadK(t + 1);

        // ---- no-max softmax: pp = exp2(S) ------------------------------
        s16x8 pa[2][2];
        #pragma unroll
        for (int qt2 = 0; qt2 < 2; ++qt2) {
            float pp[16];
            #pragma unroll
            for (int r = 0; r < 16; ++r)
                pp[r] = exp2f(S[qt2][r]);
            float ls = (((pp[0] + pp[1]) + (pp[2] + pp[3]))
                     + ((pp[4] + pp[5]) + (pp[6] + pp[7])))
                     + (((pp[8] + pp[9]) + (pp[10] + pp[11]))
                     + ((pp[12] + pp[13]) + (pp[14] + pp[15])));
            if (qt2 == 0) l_acc0 += ls; else l_acc1 += ls;
            u32 W[8];
            #pragma unroll
            for (int c = 0; c < 4; ++c) {
                W[2 * c + 0] = cvtpk(pp[4 * c + 0], pp[4 * c + 1]);
                W[2 * c + 1] = cvtpk(pp[4 * c + 2], pp[4 * c + 3]);
            }
            asm("v_permlane32_swap_b32 %0, %1" : "+v"(W[0]), "+v"(W[2]));
            asm("v_permlane32_swap_b32 %0, %1" : "+v"(W[1]), "+v"(W[3]));
            asm("v_permlane32_swap_b32 %0, %1" : "+v"(W[4]), "+v"(W[6]));
            asm("v_permlane32_swap_b32 %0, %1" : "+v"(W[5]), "+v"(W[7]));
            u32x4 lo, hi;
            lo[0] = W[0]; lo[1] = W[1]; lo[2] = W[2]; lo[3] = W[3];
            hi[0] = W[4]; hi[1] = W[5]; hi[2] = W[6]; hi[3] = W[7];
            pa[qt2][0] = __builtin_bit_cast(s16x8, lo);
            pa[qt2][1] = __builtin_bit_cast(s16x8, hi);
        }

        // ---- PV: O[q][w] += P x V --------------------------------------
        __builtin_amdgcn_s_setprio(1);
        #pragma unroll
        for (int qt2 = 0; qt2 < 2; ++qt2)
            #pragma unroll
            for (int wt = 0; wt < 2; ++wt)
                #pragma unroll
                for (int t2 = 0; t2 < 2; ++t2)
                    O[qt2][wt] = __builtin_amdgcn_mfma_f32_32x32x16_bf16(
                        pa[qt2][t2], vf[wt * 2 + t2], O[qt2][wt], 0, 0, 0);
        __builtin_amdgcn_s_setprio(0);
        if (t < 31) loadV(t + 1);
    }

    // ---- l reduction: h32 pair then cross-wave via LDS ------------------
    float ls0 = l_acc0 + __shfl_xor(l_acc0, 32);
    float ls1 = l_acc1 + __shfl_xor(l_acc1, 32);
    if (lane < 32) {
        lw[qg][0][kq][l31] = ls0;
        lw[qg][1][kq][l31] = ls1;
    }

    // ---- O reduction across the 4 kq waves; write final output ----------
    const float cnt = (float)cntb[b];
    const int grp = tid >> 8;          // q-group of this thread (0/1)
    const int tt  = tid & 255;
    const int qr  = tt >> 3;           // 0..31
    const int w8  = (tt & 7) * 4;      // 0..28
    #pragma unroll
    for (int qt2 = 0; qt2 < 2; ++qt2)
        #pragma unroll
        for (int wt = 0; wt < 2; ++wt) {
            __syncthreads();
            f32x16 oo = O[qt2][wt];
            #pragma unroll
            for (int r = 0; r < 16; ++r)
                Ored[qg][kq][(r & 3) + 8 * (r >> 2) + 4 * h32][l31] = oo[r];
            __syncthreads();
            float4 s  = *reinterpret_cast<const float4*>(&Ored[grp][0][qr][w8]);
            float4 s1 = *reinterpret_cast<const float4*>(&Ored[grp][1][qr][w8]);
            float4 s2 = *reinterpret_cast<const float4*>(&Ored[grp][2][qr][w8]);
            float4 s3 = *reinterpret_cast<const float4*>(&Ored[grp][3][qr][w8]);
            float l = (lw[grp][qt2][0][qr] + lw[grp][qt2][1][qr]
                     + lw[grp][qt2][2][qr] + lw[grp][qt2][3][qr]) - cnt;
            float inv = 1.f / l;
            int qglob = qt * 128 + grp * 64 + qt2 * 32 + qr;
            float4 o;
            o.x = (s.x + s1.x + s2.x + s3.x) * inv;
            o.y = (s.y + s1.y + s2.y + s3.y) * inv;
            o.z = (s.z + s1.z + s2.z + s3.z) * inv;
            o.w = (s.w + s1.w + s2.w + s3.w) * inv;
            *reinterpret_cast<float4*>(
                &out[((size_t)b * 2048 + qglob) * 512 + hh * 64 + wt * 32 + w8]) = o;
        }
}

extern "C" void kernel_launch(void* const* d_in, const int* in_sizes, int n_in,
                              void* d_out, int out_size, void* d_ws, size_t ws_size,
                              hipStream_t stream)
{
    const float* q    = (const float*)d_in[0];
    const float* k    = (const float*)d_in[1];
    const int*   mask = (const int*)  d_in[2];
    const float* Wq   = (const float*)d_in[3];
    const float* bq   = (const float*)d_in[4];
    const float* Wk   = (const float*)d_in[5];
    const float* bk   = (const float*)d_in[6];
    const float* Wv   = (const float*)d_in[7];
    const float* bv   = (const float*)d_in[8];
    float* out = (float*)d_out;

    // no aliasing: every buffer has a private range (total ~33.5MB)
    unsigned short* p = (unsigned short*)d_ws;
    unsigned short* qh  = p; p += (size_t)2 * 8 * 2048 * 64;   // 4MB
    unsigned short* kh  = p; p += (size_t)2 * 8 * 4096 * 64;   // 8MB
    unsigned short* vt  = p; p += (size_t)2 * 8 * 4096 * 64;   // 8MB
    unsigned short* qbf = p; p += (size_t)2 * 2048 * 512;      // 4MB
    unsigned short* kbf = p; p += (size_t)2 * 4096 * 512;      // 8MB
    unsigned short* wtq = p; p += 512 * 512;
    unsigned short* wtk = p; p += 512 * 512;
    unsigned short* wtv = p; p += 512 * 512;
    int* cntb = (int*)p;                                        // 2 ints

    dim3 blk(256);
    prep<<<dim3(3266), blk, 0, stream>>>(q, k, Wq, Wk, Wv, mask,
                                         qbf, kbf, wtq, wtk, wtv, cntb);
    proj3<<<dim3(1280), blk, 0, stream>>>(qbf, kbf, wtq, wtk, wtv,
                                          bq, bk, bv, mask, qh, kh, vt);
    attn11<<<dim3(256), dim3(512), 0, stream>>>(qh, kh, vt, cntb, out);
}